// Round 9
// baseline (117.292 us; speedup 1.0000x reference)
//
#include <hip/hip_runtime.h>
#include <string.h>

// VLAD pooling: B=16, S=1024, D=512, KC=12, K=10, fp32.
// Ledger (measured): ws poison fill ~43.5 us/iter (unconditional) +
// single-kernel residual ~6.5-8.5 us (r1/r5). Two-kernel configs carry
// ~25-30 us beyond the fill regardless of K1 shape (r0/r2/r4/r8) —
// attributed to dispatch serialization OR an invisible K1 cost.
// This round: ONE dispatch. K1 (512 chunk blocks) + per-batch completion
// counter + 160 finisher blocks that spin on ctr[b]==32 then do K2's row.
// No grid.sync (r3: ~60 us). Finishers overlap K1's tail (per-batch
// pipelining). Cross-XCD: part/asum via agent-scope stores/loads (bypass
// non-coherent per-XCD L2), ctr via device-scope atomicAdd (m20).
// ctr[16] zeroed by a 64B hipMemsetAsync before launch (graph-safe).

#define B_   16
#define S_   1024
#define D_   512
#define KC_  12
#define K_   10
#define CH_  32            // chunks per batch
#define SCH_ (S_ / CH_)    // 32 pixels per chunk
#define NT   512
#define NPAR 4             // pixel parities
#define NPX  (SCH_ / NPAR) // 8 pixels per thread

#define PART_ELEMS ((size_t)B_ * K_ * CH_ * D_)   // 2,621,440 floats

__device__ __forceinline__ void store_f4_agent(float* p, float v0, float v1,
                                               float v2, float v3) {
    unsigned long long u0, u1;
    float t0[2] = {v0, v1}, t1[2] = {v2, v3};
    memcpy(&u0, t0, 8); memcpy(&u1, t1, 8);
    __hip_atomic_store((unsigned long long*)p, u0,
                       __ATOMIC_RELAXED, __HIP_MEMORY_SCOPE_AGENT);
    __hip_atomic_store(((unsigned long long*)p) + 1, u1,
                       __ATOMIC_RELAXED, __HIP_MEMORY_SCOPE_AGENT);
}
__device__ __forceinline__ float2 load_f2_agent(const float* p) {
    unsigned long long u = __hip_atomic_load((const unsigned long long*)p,
                                             __ATOMIC_RELAXED, __HIP_MEMORY_SCOPE_AGENT);
    float2 v; memcpy(&v, &u, 8); return v;
}

__global__ __launch_bounds__(NT, 4) void vlad_all(
    const float* __restrict__ feat, const float* __restrict__ score,
    const float* __restrict__ cluster, float* __restrict__ out,
    int* __restrict__ ctr, float* __restrict__ part, float* __restrict__ asum_part)
{
    const int bid = blockIdx.x;
    const int b   = bid >> 5;          // CH_ = 32
    const int c   = bid & (CH_ - 1);
    const int s0  = c * SCH_;
    const int tid = threadIdx.x;
    const int par = tid >> 7;          // 0..3, wave-pair-uniform
    const int col = tid & 127;         // float4 column in D
    const int lane = tid & 63;
    const int wave = tid >> 6;

    __shared__ float  As[SCH_][KC_];            // 1.5 KB
    __shared__ float4 red[NPAR - 1][K_][128];   // 60 KB parity partials
    __shared__ float4 red2[3][128];             // 6 KB (phase 2)
    __shared__ float  asumS;
    __shared__ float  wsum2[2];

    // ---- phase 1a: softmax, tid<32, one pixel each; asum via shuffle ----
    if (tid < SCH_) {
        const float4* sp = (const float4*)(score + (size_t)(b * S_ + s0 + tid) * KC_);
        const float4 w0 = sp[0], w1 = sp[1], w2 = sp[2];
        float x[KC_] = {w0.x, w0.y, w0.z, w0.w, w1.x, w1.y, w1.z, w1.w,
                        w2.x, w2.y, w2.z, w2.w};
        float m = x[0];
        #pragma unroll
        for (int k = 1; k < KC_; k++) m = fmaxf(m, x[k]);
        float sum = 0.f;
        #pragma unroll
        for (int k = 0; k < KC_; k++) { x[k] = __expf(x[k] - m); sum += x[k]; }
        const float inv = 1.0f / sum;
        #pragma unroll
        for (int k = 0; k < KC_; k++) x[k] *= inv;
        *(float4*)&As[tid][0] = make_float4(x[0], x[1], x[2],  x[3]);
        *(float4*)&As[tid][4] = make_float4(x[4], x[5], x[6],  x[7]);
        *(float4*)&As[tid][8] = make_float4(x[8], x[9], x[10], x[11]);
        #pragma unroll
        for (int k = 0; k < K_; k++) {
            float r = x[k];
            r += __shfl_down(r, 16, 32);
            r += __shfl_down(r, 8, 32);
            r += __shfl_down(r, 4, 32);
            r += __shfl_down(r, 2, 32);
            r += __shfl_down(r, 1, 32);
            if (tid == 0)
                __hip_atomic_store(&asum_part[(b * CH_ + c) * K_ + k], r,
                                   __ATOMIC_RELAXED, __HIP_MEMORY_SCOPE_AGENT);
        }
    }
    __syncthreads();

    // ---- phase 1b: accumulate 8 pixels/thread over 10 clusters ----
    const float4* fp = (const float4*)(feat + (size_t)(b * S_ + s0) * D_) + col;
    float acc[K_][4];
    #pragma unroll
    for (int k = 0; k < K_; k++)
        acc[k][0] = acc[k][1] = acc[k][2] = acc[k][3] = 0.f;

    #pragma unroll
    for (int i = 0; i < NPX; i++) {
        const int s = i * NPAR + par;
        const float4 v  = fp[(size_t)s * 128];
        const float4 a0 = *(const float4*)&As[s][0];   // uniform broadcasts
        const float4 a1 = *(const float4*)&As[s][4];
        const float2 a2 = *(const float2*)&As[s][8];
        const float a[K_] = {a0.x, a0.y, a0.z, a0.w, a1.x, a1.y, a1.z, a1.w,
                             a2.x, a2.y};
        #pragma unroll
        for (int k = 0; k < K_; k++) {
            acc[k][0] += a[k] * v.x;
            acc[k][1] += a[k] * v.y;
            acc[k][2] += a[k] * v.z;
            acc[k][3] += a[k] * v.w;
        }
    }

    // ---- phase 1c: parity combine, agent-scope part store ----
    if (par) {
        #pragma unroll
        for (int k = 0; k < K_; k++)
            red[par - 1][k][col] =
                make_float4(acc[k][0], acc[k][1], acc[k][2], acc[k][3]);
    }
    __syncthreads();
    if (!par) {
        float* pp = part + (((size_t)(b * K_) * CH_ + c) * D_) + col * 4;
        #pragma unroll
        for (int k = 0; k < K_; k++) {
            float v0 = acc[k][0], v1 = acc[k][1], v2 = acc[k][2], v3 = acc[k][3];
            #pragma unroll
            for (int p = 0; p < NPAR - 1; p++) {
                const float4 t = red[p][k][col];
                v0 += t.x; v1 += t.y; v2 += t.z; v3 += t.w;
            }
            store_f4_agent(pp + (size_t)k * CH_ * D_, v0, v1, v2, v3);
        }
    }
    __syncthreads();               // all stores vmcnt-drained before signal
    if (tid == 0) {
        __threadfence();           // release
        atomicAdd(&ctr[b], 1);     // device-scope (m20)
    }

    // ---- phase 2: finisher blocks (10 per batch, inside own chunk range) ----
    if ((bid & 31) < K_) {
        const int b2 = bid >> 5;
        const int k2 = bid & 31;
        if (tid == 0) {
            while (__hip_atomic_load(&ctr[b2], __ATOMIC_ACQUIRE,
                                     __HIP_MEMORY_SCOPE_AGENT) < CH_)
                __builtin_amdgcn_s_sleep(8);
        }
        __syncthreads();           // spin done -> whole block proceeds

        const int cg   = tid >> 7;     // chunk group 0..3 (8 chunks each)
        const int dcol = tid & 127;    // float4 column

        const float* base =
            part + (((size_t)(b2 * K_ + k2) * CH_) + cg * 8) * D_ + dcol * 4;
        float4 a = make_float4(0.f, 0.f, 0.f, 0.f);
        #pragma unroll
        for (int cc = 0; cc < 8; cc++) {
            const float2 lo = load_f2_agent(base + (size_t)cc * D_);
            const float2 hi = load_f2_agent(base + (size_t)cc * D_ + 2);
            a.x += lo.x; a.y += lo.y; a.z += hi.x; a.w += hi.y;
        }

        if (tid < CH_) {
            float r = __hip_atomic_load(&asum_part[(b2 * CH_ + tid) * K_ + k2],
                                        __ATOMIC_RELAXED, __HIP_MEMORY_SCOPE_AGENT);
            r += __shfl_down(r, 16, 32);
            r += __shfl_down(r, 8, 32);
            r += __shfl_down(r, 4, 32);
            r += __shfl_down(r, 2, 32);
            r += __shfl_down(r, 1, 32);
            if (tid == 0) asumS = r;
        }
        if (cg) red2[cg - 1][dcol] = a;
        __syncthreads();

        float4 r4;
        float  sq = 0.f;
        if (!cg) {                      // tid < 128
            const float4 r0 = red2[0][dcol], r1 = red2[1][dcol], r2 = red2[2][dcol];
            const float4 cv = ((const float4*)(cluster + (size_t)k2 * D_))[dcol];
            const float asv = asumS;
            r4.x = a.x + r0.x + r1.x + r2.x - asv * cv.x;
            r4.y = a.y + r0.y + r1.y + r2.y - asv * cv.y;
            r4.z = a.z + r0.z + r1.z + r2.z - asv * cv.z;
            r4.w = a.w + r0.w + r1.w + r2.w - asv * cv.w;
            sq = r4.x * r4.x + r4.y * r4.y + r4.z * r4.z + r4.w * r4.w;
            #pragma unroll
            for (int off = 32; off > 0; off >>= 1) sq += __shfl_down(sq, off, 64);
            if (lane == 0) wsum2[wave] = sq;    // waves 0,1
        }
        __syncthreads();
        if (!cg) {
            const float tot   = wsum2[0] + wsum2[1];
            const float scale = rsqrtf(fmaxf(tot, 1e-12f));
            ((float4*)(out + (size_t)(b2 * K_ + k2) * D_))[dcol] =
                make_float4(r4.x * scale, r4.y * scale, r4.z * scale, r4.w * scale);
        }
    }
}

extern "C" void kernel_launch(void* const* d_in, const int* in_sizes, int n_in,
                              void* d_out, int out_size, void* d_ws, size_t ws_size,
                              hipStream_t stream) {
    const float* feat    = (const float*)d_in[0];
    const float* score   = (const float*)d_in[1];
    const float* cluster = (const float*)d_in[2];
    float* out = (float*)d_out;

    int*   ctr       = (int*)d_ws;                          // 16 ints (64 B)
    float* part      = (float*)((char*)d_ws + 256);         // B*K*CH*D fp32
    float* asum_part = part + PART_ELEMS;                   // B*CH*K fp32

    hipMemsetAsync(ctr, 0, 64, stream);                     // zero counters
    vlad_all<<<B_ * CH_, NT, 0, stream>>>(feat, score, cluster, out,
                                          ctr, part, asum_part);
}